// Round 2
// baseline (117.396 us; speedup 1.0000x reference)
//
#include <hip/hip_runtime.h>
#include <stdint.h>
#include <math.h>

// CategoricalSampler: reproduce jax.random.categorical(jax.random.key(42), log_softmax(logits/T), axis=-1)
// == argmax_v( logits[b,s,v]/T + gumbel(b,s,v) )  (log_softmax shift cancels in argmax).
//
// RNG scheme A (jax_threefry_partitionable=True path, 32-bit draws):
//   bits[i] = x0 ^ x1 of threefry2x32-20(key=(0,42), ctr=(i>>32, i&0xffffffff)), i = flat index.
//   (Round 0 tested x1 alone — failed. 64-bit path is x0<<32|x1; 32-bit XORs the pair.)

constexpr int V = 128000;
constexpr int NROWS = 256;   // B*S = 32*8
constexpr int TPB = 1024;

__device__ __forceinline__ void tf_round(uint32_t& x0, uint32_t& x1, const int r) {
  x0 += x1;
  x1 = (x1 << r) | (x1 >> (32 - r));
  x1 ^= x0;
}

// Threefry-2x32-20 with key (k1=0, k2=42), counter (hi=0, lo=ctr); returns x0 ^ x1.
__device__ __forceinline__ uint32_t threefry_xor(uint32_t ctr) {
  constexpr uint32_t ks0 = 0u;
  constexpr uint32_t ks1 = 42u;
  constexpr uint32_t ks2 = 0x1BD11BDAu ^ ks0 ^ ks1;
  uint32_t x0 = 0u + ks0;    // hi counter word (0) + ks0
  uint32_t x1 = ctr + ks1;   // lo counter word + ks1
  tf_round(x0, x1, 13); tf_round(x0, x1, 15); tf_round(x0, x1, 26); tf_round(x0, x1, 6);
  x0 += ks1; x1 += ks2 + 1u;
  tf_round(x0, x1, 17); tf_round(x0, x1, 29); tf_round(x0, x1, 16); tf_round(x0, x1, 24);
  x0 += ks2; x1 += ks0 + 2u;
  tf_round(x0, x1, 13); tf_round(x0, x1, 15); tf_round(x0, x1, 26); tf_round(x0, x1, 6);
  x0 += ks0; x1 += ks1 + 3u;
  tf_round(x0, x1, 17); tf_round(x0, x1, 29); tf_round(x0, x1, 16); tf_round(x0, x1, 24);
  x0 += ks1; x1 += ks2 + 4u;
  tf_round(x0, x1, 13); tf_round(x0, x1, 15); tf_round(x0, x1, 26); tf_round(x0, x1, 6);
  x0 += ks2; x1 += ks0 + 5u;
  return x0 ^ x1;
}

__global__ __launch_bounds__(TPB) void CategoricalSampler_kernel(
    const float* __restrict__ logits, const float* __restrict__ temp,
    int* __restrict__ out) {
  const int row = blockIdx.x;
  const int t   = threadIdx.x;
  const float T = temp[0];
  const float* rowp = logits + (size_t)row * (size_t)V;
  const uint32_t base = (uint32_t)row * (uint32_t)V;

  float best = -INFINITY;
  int bestIdx = 0;

  // 125 strided, coalesced iterations per thread.
  for (int v = t; v < V; v += TPB) {
    const uint32_t bits = threefry_xor(base + (uint32_t)v);
    // JAX uniform(minval=tiny, maxval=1): f = bitcast((bits>>9)|0x3f800000) - 1 in [0,1);
    // u = max(tiny, f + tiny) == (f==0 ? tiny : f) exactly in f32.
    const float f = __uint_as_float((bits >> 9) | 0x3f800000u) - 1.0f;
    const float u = (f == 0.0f) ? 1.17549435e-38f : f;
    const float g = -logf(-logf(u));            // gumbel
    const float val = g + rowp[v] / T;
    if (val > best) { best = val; bestIdx = v; }   // strict > keeps earliest index
  }

  __shared__ float sv[TPB];
  __shared__ int   si[TPB];
  sv[t] = best; si[t] = bestIdx;
  __syncthreads();
  for (int s = TPB / 2; s > 0; s >>= 1) {
    if (t < s) {
      const float ov = sv[t + s]; const int oi = si[t + s];
      if (ov > sv[t] || (ov == sv[t] && oi < si[t])) { sv[t] = ov; si[t] = oi; }
    }
    __syncthreads();
  }
  if (t == 0) out[row] = si[0];
}

extern "C" void kernel_launch(void* const* d_in, const int* in_sizes, int n_in,
                              void* d_out, int out_size, void* d_ws, size_t ws_size,
                              hipStream_t stream) {
  const float* logits = (const float*)d_in[0];
  const float* temp   = (const float*)d_in[1];
  int* out = (int*)d_out;
  CategoricalSampler_kernel<<<NROWS, TPB, 0, stream>>>(logits, temp, out);
}

// Round 3
// 95.714 us; speedup vs baseline: 1.2265x; 1.2265x over previous
//
#include <hip/hip_runtime.h>
#include <stdint.h>
#include <math.h>

// CategoricalSampler: reproduce jax.random.categorical(jax.random.key(42), log_softmax(logits/T), axis=-1)
// == argmax_v( logits[b,s,v]/T + gumbel(b,s,v) )  (log_softmax shift cancels in argmax).
//
// RNG (verified R2, absmax=0): bits[i] = x0 ^ x1 of threefry2x32-20(key=(0,42), ctr=(0, i)).
//
// Monotone-transform trick: compare in log2 units.
//   (l/T + g) * log2e = l*(log2e/T) + (-log2(-log2 u)) + C,  C = -log2(ln 2) uniform -> drops.
// Two hardware v_log_f32 ops replace two software logf expansions.

constexpr int V = 128000;
constexpr int NROWS = 256;   // B*S = 32*8
constexpr int SPLIT = 4;     // blocks per row -> 1024 blocks -> 100% occupancy
constexpr int SEG = V / SPLIT;   // 32000
constexpr int TPB = 512;

__device__ __forceinline__ void tf_round(uint32_t& x0, uint32_t& x1, const int r) {
  x0 += x1;
  x1 = (x1 << r) | (x1 >> (32 - r));   // -> v_alignbit_b32
  x1 ^= x0;
}

// Threefry-2x32-20 with key (0, 42), counter (hi=0, lo=ctr); returns x0 ^ x1.
__device__ __forceinline__ uint32_t threefry_xor(uint32_t ctr) {
  constexpr uint32_t ks0 = 0u;
  constexpr uint32_t ks1 = 42u;
  constexpr uint32_t ks2 = 0x1BD11BDAu ^ ks0 ^ ks1;
  uint32_t x0 = 0u + ks0;
  uint32_t x1 = ctr + ks1;
  tf_round(x0, x1, 13); tf_round(x0, x1, 15); tf_round(x0, x1, 26); tf_round(x0, x1, 6);
  x0 += ks1; x1 += ks2 + 1u;
  tf_round(x0, x1, 17); tf_round(x0, x1, 29); tf_round(x0, x1, 16); tf_round(x0, x1, 24);
  x0 += ks2; x1 += ks0 + 2u;
  tf_round(x0, x1, 13); tf_round(x0, x1, 15); tf_round(x0, x1, 26); tf_round(x0, x1, 6);
  x0 += ks0; x1 += ks1 + 3u;
  tf_round(x0, x1, 17); tf_round(x0, x1, 29); tf_round(x0, x1, 16); tf_round(x0, x1, 24);
  x0 += ks1; x1 += ks2 + 4u;
  tf_round(x0, x1, 13); tf_round(x0, x1, 15); tf_round(x0, x1, 26); tf_round(x0, x1, 6);
  x0 += ks2; x1 += ks0 + 5u;
  return x0 ^ x1;
}

__global__ __launch_bounds__(TPB) void CategoricalSampler_stage1(
    const float* __restrict__ logits, const float* __restrict__ temp,
    float2* __restrict__ ws) {
  const int row = blockIdx.x / SPLIT;
  const int seg = blockIdx.x % SPLIT;
  const int t   = threadIdx.x;
  // l/T then *log2e == l*(log2e/T) up to 1ulp; T==1.0 here so exact either way.
  const float scale = 1.4426950408889634f / temp[0];
  const float* rowp = logits + (size_t)row * (size_t)V;
  const uint32_t base = (uint32_t)row * (uint32_t)V;

  float best = -INFINITY;
  int bestIdx = 0;

  const int vend = (seg + 1) * SEG;
  for (int v = seg * SEG + t; v < vend; v += TPB) {
    const uint32_t bits = threefry_xor(base + (uint32_t)v);
    // JAX uniform: f = bitcast((bits>>9)|0x3f800000) - 1 in [0,1); u = (f==0 ? tiny : f).
    const float f = __uint_as_float((bits >> 9) | 0x3f800000u) - 1.0f;
    const float u = (f == 0.0f) ? 1.17549435e-38f : f;
    const float w  = -__log2f(u);      // in (0, 126]
    const float g2 = -__log2f(w);      // gumbel, log2 units (uniform const dropped)
    const float val = fmaf(rowp[v], scale, g2);
    if (val > best) { best = val; bestIdx = v; }   // strict > keeps earliest index
  }

  __shared__ float sv[TPB];
  __shared__ int   si[TPB];
  sv[t] = best; si[t] = bestIdx;
  __syncthreads();
  for (int s = TPB / 2; s > 0; s >>= 1) {
    if (t < s) {
      const float ov = sv[t + s]; const int oi = si[t + s];
      if (ov > sv[t] || (ov == sv[t] && oi < si[t])) { sv[t] = ov; si[t] = oi; }
    }
    __syncthreads();
  }
  if (t == 0) ws[blockIdx.x] = make_float2(sv[0], __int_as_float(si[0]));
}

__global__ __launch_bounds__(NROWS) void CategoricalSampler_stage2(
    const float2* __restrict__ ws, int* __restrict__ out) {
  const int r = threadIdx.x;   // one thread per row
  float best = -INFINITY;
  int bestIdx = 0;
  for (int s = 0; s < SPLIT; ++s) {
    const float2 p = ws[r * SPLIT + s];
    const int idx = __float_as_int(p.y);
    if (p.x > best || (p.x == best && idx < bestIdx)) { best = p.x; bestIdx = idx; }
  }
  out[r] = bestIdx;
}

extern "C" void kernel_launch(void* const* d_in, const int* in_sizes, int n_in,
                              void* d_out, int out_size, void* d_ws, size_t ws_size,
                              hipStream_t stream) {
  const float* logits = (const float*)d_in[0];
  const float* temp   = (const float*)d_in[1];
  int* out = (int*)d_out;
  float2* ws = (float2*)d_ws;   // NROWS*SPLIT float2 = 8 KB
  CategoricalSampler_stage1<<<NROWS * SPLIT, TPB, 0, stream>>>(logits, temp, ws);
  CategoricalSampler_stage2<<<1, NROWS, 0, stream>>>(ws, out);
}

// Round 5
// 91.037 us; speedup vs baseline: 1.2895x; 1.0514x over previous
//
#include <hip/hip_runtime.h>
#include <stdint.h>
#include <math.h>

// CategoricalSampler: argmax_v( logits[b,s,v]*(log2e/T) + g2(v) ), g2 = -log2(-log2 u),
// u from JAX threefry2x32-20 partitionable path: bits[i] = x0^x1, key=(0,42), ctr=(0, i).
// Bit-scheme verified R2; log2-units value path verified R3 (absmax=0).
//
// R4 post-mortem: w = 23 - log2f(float(m)) cancels catastrophically for u near 1
// (the argmax winners!) — abs err ~1ULP@23 vs w ~ 1e-7. Must use direct __log2f(u):
// hardware log's ~1ULP error is RELATIVE to the tiny result, preserving order.

constexpr int V = 128000;
constexpr int NROWS = 256;       // B*S
constexpr int SPLIT = 5;         // segments per row -> grid 1280 = 5 blocks/CU exact
constexpr int SEG = V / SPLIT;   // 25600
constexpr int TPB = 256;
constexpr int J = SEG / (TPB * 4);  // 25 exact iterations, 4 elems each

__device__ __forceinline__ void tf_round(uint32_t& x0, uint32_t& x1, const int r) {
  x0 += x1;
  x1 = (x1 << r) | (x1 >> (32 - r));   // -> v_alignbit_b32
  x1 ^= x0;
}

// Threefry-2x32-20, key (0,42), counter (0, ctr); returns x0 ^ x1.
__device__ __forceinline__ uint32_t threefry_xor(uint32_t ctr) {
  constexpr uint32_t ks0 = 0u;
  constexpr uint32_t ks1 = 42u;
  constexpr uint32_t ks2 = 0x1BD11BDAu ^ ks0 ^ ks1;
  uint32_t x0 = 0u + ks0;
  uint32_t x1 = ctr + ks1;
  tf_round(x0, x1, 13); tf_round(x0, x1, 15); tf_round(x0, x1, 26); tf_round(x0, x1, 6);
  x0 += ks1; x1 += ks2 + 1u;
  tf_round(x0, x1, 17); tf_round(x0, x1, 29); tf_round(x0, x1, 16); tf_round(x0, x1, 24);
  x0 += ks2; x1 += ks0 + 2u;
  tf_round(x0, x1, 13); tf_round(x0, x1, 15); tf_round(x0, x1, 26); tf_round(x0, x1, 6);
  x0 += ks0; x1 += ks1 + 3u;
  tf_round(x0, x1, 17); tf_round(x0, x1, 29); tf_round(x0, x1, 16); tf_round(x0, x1, 24);
  x0 += ks1; x1 += ks2 + 4u;
  tf_round(x0, x1, 13); tf_round(x0, x1, 15); tf_round(x0, x1, 26); tf_round(x0, x1, 6);
  x0 += ks2; x1 += ks0 + 5u;
  return x0 ^ x1;
}

__global__ __launch_bounds__(TPB) void CategoricalSampler_stage1(
    const float* __restrict__ logits, const float* __restrict__ temp,
    float2* __restrict__ ws) {
  const int b   = blockIdx.x;
  const int row = b / SPLIT;           // block-uniform -> scalar magic-mul
  const int seg = b - row * SPLIT;
  const int t   = threadIdx.x;
  const float scale = 1.4426950408889634f / temp[0];
  const int segbase = seg * SEG;
  const float4* rp4 = reinterpret_cast<const float4*>(logits + (size_t)row * V + segbase);
  const uint32_t cb = (uint32_t)row * (uint32_t)V + (uint32_t)segbase;

  float best = -INFINITY;
  int bestIdx = 0;

  for (int j = 0; j < J; ++j) {
    const int q = j * TPB + t;                 // float4 slot: wave reads 1KB contiguous
    const float4 L = rp4[q];
    const uint32_t c0 = cb + (uint32_t)(q * 4);
    const int vbase = segbase + q * 4;
#pragma unroll
    for (int k = 0; k < 4; ++k) {              // 4 independent threefry chains -> ILP
      const uint32_t bits = threefry_xor(c0 + (uint32_t)k);
      // R3-verified value path: u = bitcast((bits>>9)|one) - 1 in [0,1); f==0 -> tiny.
      const float f = __uint_as_float((bits >> 9) | 0x3f800000u) - 1.0f;
      const float u = (f == 0.0f) ? 1.17549435e-38f : f;
      const float w  = -__log2f(u);            // in (0, 126]
      const float s  = __log2f(w);             // g2 = -s
      const float lk = (k == 0) ? L.x : (k == 1) ? L.y : (k == 2) ? L.z : L.w;
      const float val = fmaf(lk, scale, -s);
      const int idx = vbase + k;
      if (val > best) { best = val; bestIdx = idx; }  // ascending v: strict > keeps earliest
    }
  }

  __shared__ float sv[TPB];
  __shared__ int   si[TPB];
  sv[t] = best; si[t] = bestIdx;
  __syncthreads();
  for (int s2 = TPB / 2; s2 > 0; s2 >>= 1) {
    if (t < s2) {
      const float ov = sv[t + s2]; const int oi = si[t + s2];
      if (ov > sv[t] || (ov == sv[t] && oi < si[t])) { sv[t] = ov; si[t] = oi; }
    }
    __syncthreads();
  }
  if (t == 0) ws[b] = make_float2(sv[0], __int_as_float(si[0]));
}

__global__ __launch_bounds__(NROWS) void CategoricalSampler_stage2(
    const float2* __restrict__ ws, int* __restrict__ out) {
  const int r = threadIdx.x;   // one thread per row
  float best = -INFINITY;
  int bestIdx = 0;
  for (int s = 0; s < SPLIT; ++s) {
    const float2 p = ws[r * SPLIT + s];
    const int idx = __float_as_int(p.y);
    if (p.x > best || (p.x == best && idx < bestIdx)) { best = p.x; bestIdx = idx; }
  }
  out[r] = bestIdx;
}

extern "C" void kernel_launch(void* const* d_in, const int* in_sizes, int n_in,
                              void* d_out, int out_size, void* d_ws, size_t ws_size,
                              hipStream_t stream) {
  const float* logits = (const float*)d_in[0];
  const float* temp   = (const float*)d_in[1];
  int* out = (int*)d_out;
  float2* ws = (float2*)d_ws;   // NROWS*SPLIT float2 = 10 KB
  CategoricalSampler_stage1<<<NROWS * SPLIT, TPB, 0, stream>>>(logits, temp, ws);
  CategoricalSampler_stage2<<<1, NROWS, 0, stream>>>(ws, out);
}

// Round 6
// 76.081 us; speedup vs baseline: 1.5431x; 1.1966x over previous
//
#include <hip/hip_runtime.h>
#include <stdint.h>
#include <math.h>

// CategoricalSampler: argmax_v( logits[b,s,v]*(log2e/T) + g2(v) ), g2 = -log2(-log2 u),
// u from JAX threefry2x32-20 partitionable path: bits[i] = x0^x1, key=(0,42), ctr=(0, i).
// Bit-scheme verified R2; log2-units value path verified R3/R5 (absmax=0).
//
// R4 lesson: never compute -log2(u) by cancellation (23 - log2(m)) — kills precision at
// the argmax winners (u near 1). Direct __log2f keeps error relative to the tiny result.
// f==0 guard dropped (R6): u=0 -> log2(0)=-inf -> val=-inf, loses identically; no NaN.

constexpr int V = 128000;
constexpr int NROWS = 256;       // B*S
constexpr int TPB = 256;

__device__ __forceinline__ uint32_t rotl_(uint32_t x, uint32_t r) {
#if __has_builtin(__builtin_amdgcn_alignbit)
  return __builtin_amdgcn_alignbit(x, x, 32u - r);   // 1x v_alignbit_b32, guaranteed
#else
  return (x << r) | (x >> (32u - r));
#endif
}

// Threefry-2x32-20, key (0,42), counter (0, ctr); returns x0 ^ x1.
__device__ __forceinline__ uint32_t threefry_xor(uint32_t ctr) {
  constexpr uint32_t ks0 = 0u;
  constexpr uint32_t ks1 = 42u;
  constexpr uint32_t ks2 = 0x1BD11BDAu ^ ks0 ^ ks1;
  uint32_t x0 = 0u + ks0;
  uint32_t x1 = ctr + ks1;
#define TFR(r) { x0 += x1; x1 = rotl_(x1, r); x1 ^= x0; }
  TFR(13) TFR(15) TFR(26) TFR(6)
  x0 += ks1; x1 += ks2 + 1u;
  TFR(17) TFR(29) TFR(16) TFR(24)
  x0 += ks2; x1 += ks0 + 2u;
  TFR(13) TFR(15) TFR(26) TFR(6)
  x0 += ks0; x1 += ks1 + 3u;
  TFR(17) TFR(29) TFR(16) TFR(24)
  x0 += ks1; x1 += ks2 + 4u;
  TFR(13) TFR(15) TFR(26) TFR(6)
  x0 += ks2; x1 += ks0 + 5u;
#undef TFR
  return x0 ^ x1;
}

template <int SPLIT>
__global__ __launch_bounds__(TPB) void CategoricalSampler_stage1(
    const float* __restrict__ logits, const float* __restrict__ temp,
    float2* __restrict__ ws) {
  constexpr int SEG = V / SPLIT;
  constexpr int J = SEG / (TPB * 4);   // exact by construction
  const int b   = blockIdx.x;
  const int row = b / SPLIT;           // block-uniform -> scalar ops
  const int seg = b - row * SPLIT;
  const int t   = threadIdx.x;
  const float scale = 1.4426950408889634f / temp[0];
  const int segbase = seg * SEG;
  const float4* rp4 = reinterpret_cast<const float4*>(logits + (size_t)row * V + segbase);
  const uint32_t cb = (uint32_t)row * (uint32_t)V + (uint32_t)segbase;

  float best = -INFINITY;
  int bestIdx = 0;

#pragma unroll
  for (int j = 0; j < J; ++j) {
    const int q = j * TPB + t;                 // float4 slot: wave reads 1KB contiguous
    const float4 L = rp4[q];
    const uint32_t c0 = cb + (uint32_t)(q * 4);
    const int vbase = segbase + q * 4;
#pragma unroll
    for (int k = 0; k < 4; ++k) {              // 4 independent threefry chains -> ILP
      const uint32_t bits = threefry_xor(c0 + (uint32_t)k);
      // u in [0,1); u==0 -> val=-inf (loses; no NaN). Negations fold to VOP3 modifiers.
      const float u = __uint_as_float((bits >> 9) | 0x3f800000u) - 1.0f;
      const float s1 = __log2f(u);             // <= 0, -inf at u=0
      const float s2 = __log2f(-s1);           // g2 = -s2
      const float lk = (k == 0) ? L.x : (k == 1) ? L.y : (k == 2) ? L.z : L.w;
      const float val = fmaf(lk, scale, -s2);
      const int idx = vbase + k;
      if (val > best) { best = val; bestIdx = idx; }  // ascending v: strict > keeps earliest
    }
  }

  // wave-level argmax (64 lanes), lower index wins ties
#pragma unroll
  for (int off = 32; off > 0; off >>= 1) {
    const float ov = __shfl_down(best, off);
    const int   oi = __shfl_down(bestIdx, off);
    if (ov > best || (ov == best && oi < bestIdx)) { best = ov; bestIdx = oi; }
  }

  __shared__ float sv[TPB / 64];
  __shared__ int   si[TPB / 64];
  const int wid = t >> 6;
  if ((t & 63) == 0) { sv[wid] = best; si[wid] = bestIdx; }
  __syncthreads();
  if (t == 0) {
    float bv = sv[0]; int bi = si[0];
#pragma unroll
    for (int w = 1; w < TPB / 64; ++w) {
      if (sv[w] > bv || (sv[w] == bv && si[w] < bi)) { bv = sv[w]; bi = si[w]; }
    }
    ws[b] = make_float2(bv, __int_as_float(bi));
  }
}

template <int SPLIT>
__global__ __launch_bounds__(NROWS) void CategoricalSampler_stage2(
    const float2* __restrict__ ws, int* __restrict__ out) {
  const int r = threadIdx.x;   // one thread per row
  float best = -INFINITY;
  int bestIdx = 0;
  for (int s = 0; s < SPLIT; ++s) {
    const float2 p = ws[r * SPLIT + s];
    const int idx = __float_as_int(p.y);
    if (p.x > best || (p.x == best && idx < bestIdx)) { best = p.x; bestIdx = idx; }
  }
  out[r] = bestIdx;
}

extern "C" void kernel_launch(void* const* d_in, const int* in_sizes, int n_in,
                              void* d_out, int out_size, void* d_ws, size_t ws_size,
                              hipStream_t stream) {
  const float* logits = (const float*)d_in[0];
  const float* temp   = (const float*)d_in[1];
  int* out = (int*)d_out;
  float2* ws = (float2*)d_ws;
  if (ws_size >= (size_t)NROWS * 25 * sizeof(float2)) {
    // grid 6400 = 25 blocks/row -> 8 resident blocks/CU -> 32 waves/CU (full pool)
    CategoricalSampler_stage1<25><<<NROWS * 25, TPB, 0, stream>>>(logits, temp, ws);
    CategoricalSampler_stage2<25><<<1, NROWS, 0, stream>>>(ws, out);
  } else {
    CategoricalSampler_stage1<5><<<NROWS * 5, TPB, 0, stream>>>(logits, temp, ws);
    CategoricalSampler_stage2<5><<<1, NROWS, 0, stream>>>(ws, out);
  }
}

// Round 7
// 70.018 us; speedup vs baseline: 1.6767x; 1.0866x over previous
//
#include <hip/hip_runtime.h>
#include <stdint.h>
#include <math.h>

// CategoricalSampler: argmax_v( logits[b,s,v]*(log2e/T) + g2(v) ), g2 = -log2(-log2 u),
// u from JAX threefry2x32-20 partitionable path: bits[i] = x0^x1, key=(0,42), ctr=(0, i).
// Bit-scheme verified R2; value path verified R3/R5/R6 (absmax=0).
//
// R4 lesson: direct __log2f(u) only — no cancellation forms (kills order at u->1 winners).
// R7: force 1-inst rotates (__builtin_rotateleft32 -> v_alignbit_b32), merge key
// injections into v_add3_u32-matchable adds (integer-exact), alignbit mantissa pack,
// inline-const jk argmax codes. All bit-identical to R6's passing math.

constexpr int V = 128000;
constexpr int NROWS = 256;       // B*S
constexpr int TPB = 256;
constexpr int SPLITQ = 25;       // grid 6400 -> 8 blocks/CU resident

__device__ __forceinline__ uint32_t rotl_(uint32_t x, uint32_t r) {
#if __has_builtin(__builtin_rotateleft32)
  return __builtin_rotateleft32(x, r);   // fshl -> single v_alignbit_b32
#else
  return (x << r) | (x >> (32u - r));
#endif
}

// Threefry-2x32-20, key (0,42), counter (0, ctr); returns x0 ^ x1.
// ks0=0, ks1=42, ks2=0x1BD11BDA^42=0x1BD11BF0. Injections merged into add3 forms.
__device__ __forceinline__ uint32_t threefry_xor(uint32_t ctr) {
  uint32_t x0, x1;
  x1 = ctr + 42u;                       // ctr_lo + ks1   (x0 = ctr_hi + ks0 = 0)
  x0 = x1;            x1 = rotl_(x1, 13) ^ x0;   // round 1: x0 = 0 + x1
  x0 += x1;           x1 = rotl_(x1, 15) ^ x0;
  x0 += x1;           x1 = rotl_(x1, 26) ^ x0;
  x0 += x1;           x1 = rotl_(x1,  6) ^ x0;
  x1 += 0x1BD11BF1u;  x0 = x0 + 42u + x1;        // inject1 (ks1 | ks2+1) + round-add fused
                      x1 = rotl_(x1, 17) ^ x0;
  x0 += x1;           x1 = rotl_(x1, 29) ^ x0;
  x0 += x1;           x1 = rotl_(x1, 16) ^ x0;
  x0 += x1;           x1 = rotl_(x1, 24) ^ x0;
  x1 += 2u;           x0 = x0 + 0x1BD11BF0u + x1; // inject2 (ks2 | ks0+2)
                      x1 = rotl_(x1, 13) ^ x0;
  x0 += x1;           x1 = rotl_(x1, 15) ^ x0;
  x0 += x1;           x1 = rotl_(x1, 26) ^ x0;
  x0 += x1;           x1 = rotl_(x1,  6) ^ x0;
  x1 += 45u;          x0 = x0 + x1;               // inject3 (ks0=0 | ks1+3) — x0 add is free
                      x1 = rotl_(x1, 17) ^ x0;
  x0 += x1;           x1 = rotl_(x1, 29) ^ x0;
  x0 += x1;           x1 = rotl_(x1, 16) ^ x0;
  x0 += x1;           x1 = rotl_(x1, 24) ^ x0;
  x1 += 0x1BD11BF4u;  x0 = x0 + 42u + x1;        // inject4 (ks1 | ks2+4)
                      x1 = rotl_(x1, 13) ^ x0;
  x0 += x1;           x1 = rotl_(x1, 15) ^ x0;
  x0 += x1;           x1 = rotl_(x1, 26) ^ x0;
  x0 += x1;           x1 = rotl_(x1,  6) ^ x0;
  return (x0 + 0x1BD11BF0u) ^ (x1 + 5u);         // inject5 (ks2 | ks0+5) folded into output
}

__device__ __forceinline__ uint32_t mant_pack(uint32_t bits) {
#if __has_builtin(__builtin_amdgcn_alignbit)
  return __builtin_amdgcn_alignbit(127u, bits, 9u);  // (127<<32|bits)>>9 = (bits>>9)|0x3f800000
#else
  return (bits >> 9) | 0x3f800000u;
#endif
}

template <int SPLIT>
__global__ __launch_bounds__(TPB) void CategoricalSampler_stage1(
    const float* __restrict__ logits, const float* __restrict__ temp,
    float2* __restrict__ ws) {
  constexpr int SEG = V / SPLIT;
  constexpr int J = SEG / (TPB * 4);   // exact by construction
  const int b   = blockIdx.x;
  const int row = b / SPLIT;           // block-uniform -> scalar ops
  const int seg = b - row * SPLIT;
  const int t   = threadIdx.x;
  const float scale = 1.4426950408889634f / temp[0];
  const int segbase = seg * SEG;
  const float4* rp4 = reinterpret_cast<const float4*>(logits + (size_t)row * V + segbase);
  const uint32_t cb = (uint32_t)row * (uint32_t)V + (uint32_t)segbase + (uint32_t)(t * 4);

  float best = -INFINITY;
  int bestCode = 0;                    // jk = j*4+k, compile-time consts

#pragma unroll
  for (int j = 0; j < J; ++j) {
    const int q = j * TPB + t;                 // float4 slot: wave reads 1KB contiguous
    const float4 L = rp4[q];
    const uint32_t c0 = cb + (uint32_t)(j * TPB * 4);
#pragma unroll
    for (int k = 0; k < 4; ++k) {              // 4 independent threefry chains -> ILP
      const uint32_t bits = threefry_xor(c0 + (uint32_t)k);
      const float u  = __uint_as_float(mant_pack(bits)) - 1.0f;  // [0,1); 0 -> val=-inf, loses
      const float s1 = __log2f(u);
      const float s2 = __log2f(-s1);           // g2 = -s2 (neg folds to VOP3 modifier)
      const float lk = (k == 0) ? L.x : (k == 1) ? L.y : (k == 2) ? L.z : L.w;
      const float val = fmaf(lk, scale, -s2);
      if (val > best) { best = val; bestCode = j * 4 + k; }  // ascending v: > keeps earliest
    }
  }

  // reconstruct global index: v = segbase + j*TPB*4 + t*4 + k
  int bestIdx = segbase + (bestCode >> 2) * (TPB * 4) + (t << 2) + (bestCode & 3);

  // wave-level argmax (64 lanes), lower index wins ties
#pragma unroll
  for (int off = 32; off > 0; off >>= 1) {
    const float ov = __shfl_down(best, off);
    const int   oi = __shfl_down(bestIdx, off);
    if (ov > best || (ov == best && oi < bestIdx)) { best = ov; bestIdx = oi; }
  }

  __shared__ float sv[TPB / 64];
  __shared__ int   si[TPB / 64];
  const int wid = t >> 6;
  if ((t & 63) == 0) { sv[wid] = best; si[wid] = bestIdx; }
  __syncthreads();
  if (t == 0) {
    float bv = sv[0]; int bi = si[0];
#pragma unroll
    for (int w = 1; w < TPB / 64; ++w) {
      if (sv[w] > bv || (sv[w] == bv && si[w] < bi)) { bv = sv[w]; bi = si[w]; }
    }
    ws[b] = make_float2(bv, __int_as_float(bi));
  }
}

template <int SPLIT>
__global__ __launch_bounds__(64) void CategoricalSampler_stage2(
    const float2* __restrict__ ws, int* __restrict__ out) {
  const int r = blockIdx.x;            // one wave per row
  const int l = threadIdx.x;
  float best = -INFINITY;
  int bestIdx = 0x7FFFFFFF;
  if (l < SPLIT) {
    const float2 p = ws[r * SPLIT + l];
    best = p.x; bestIdx = __float_as_int(p.y);
  }
#pragma unroll
  for (int off = 32; off > 0; off >>= 1) {
    const float ov = __shfl_down(best, off);
    const int   oi = __shfl_down(bestIdx, off);
    if (ov > best || (ov == best && oi < bestIdx)) { best = ov; bestIdx = oi; }
  }
  if (l == 0) out[r] = bestIdx;
}

extern "C" void kernel_launch(void* const* d_in, const int* in_sizes, int n_in,
                              void* d_out, int out_size, void* d_ws, size_t ws_size,
                              hipStream_t stream) {
  const float* logits = (const float*)d_in[0];
  const float* temp   = (const float*)d_in[1];
  int* out = (int*)d_out;
  float2* ws = (float2*)d_ws;
  if (ws_size >= (size_t)NROWS * SPLITQ * sizeof(float2)) {
    CategoricalSampler_stage1<SPLITQ><<<NROWS * SPLITQ, TPB, 0, stream>>>(logits, temp, ws);
    CategoricalSampler_stage2<SPLITQ><<<NROWS, 64, 0, stream>>>(ws, out);
  } else {
    CategoricalSampler_stage1<5><<<NROWS * 5, TPB, 0, stream>>>(logits, temp, ws);
    CategoricalSampler_stage2<5><<<NROWS, 64, 0, stream>>>(ws, out);
  }
}